// Round 13
// baseline (136.104 us; speedup 1.0000x reference)
//
#include <hip/hip_runtime.h>
#include <hip/hip_bf16.h>

// CRF NLL via chunk-parallel linear-space scan, register-resident H, 2-way
// in-wave ILP + in-wave pair fusion.
//   q^T_t = q^T_0 (M D_1)...(M D_T);  chunk: H <- diag(e_t) M^T H (16 steps).
// mfma_f32_16x16x16_bf16: B-layout == C/D-layout -> next step's B operand is
// the current C packed f32->bf16 in place (verified R8-R11, absmax 0).
//
// R12 theory: R6-R11 obey an invariant ~120 cyc per MFMA on each wave's
// serial timeline, regardless of shape/LDS-vs-reg/ILP/occupancy. Cause
// hypothesis: backend splits the unified file (C-tiles -> AGPRs; VGPR_Count
// 52..92 << live set) and under that pressure re-serializes each tile's
// depth-3 MFMA chain back-to-back => 9/18 sequential latency-bound chains.
// Fix: (a) waves_per_eu(1,1) -> 512-reg budget (pressure gone; occupancy
// is irrelevant -- R6's 1 wave/SIMD ran at the same per-MFMA rate);
// (b) MFMA block layer-interleaved across both chains (18 independent per
// layer) and PINNED with sched_group_barrier(MFMA,18)x3 so the scheduler
// cannot re-chain. Signal: VGPR_Count must jump >=160.

namespace {
constexpr int kB = 128;
constexpr int kS = 512;
constexpr int kT = 36;
constexpr int kStart = 34;
constexpr int kEnd = 35;
constexpr int kL = 16;     // steps per chunk
constexpr int kG = 16;     // pairs per batch; wave g covers steps [32g, 32g+32)
constexpr int kEStr = 48;  // Etab row stride (floats)
constexpr int kTS = 52;    // LDS transpose row stride (halfwords)

typedef __bf16 bf16x4 __attribute__((ext_vector_type(4)));
typedef short short4v __attribute__((ext_vector_type(4)));
typedef float f32x4 __attribute__((ext_vector_type(4)));
typedef int int2v __attribute__((ext_vector_type(2)));

__device__ __forceinline__ float readlane_f(float v, int lane) {
    return __builtin_bit_cast(float, __builtin_amdgcn_readlane(__builtin_bit_cast(int, v), lane));
}

__device__ __forceinline__ float wave_sum(float v) {
#pragma unroll
    for (int off = 32; off; off >>= 1) v += __shfl_xor(v, off, 64);
    return v;
}

__device__ __forceinline__ int wave_sum_i(int v) {
#pragma unroll
    for (int off = 32; off; off >>= 1) v += __shfl_xor(v, off, 64);
    return v;
}

#define MF16(a, b, c) __builtin_amdgcn_mfma_f32_16x16x16bf16_1k((a), (b), (c), 0, 0, 0)

// 27-MFMA 36x36(x48) product (single chain; used in the epilogue fusion)
#define MM27(AP, BP, CP) \
    f32x4 CP##_00 = MF16(AP##_00, BP##_00, z), CP##_01 = MF16(AP##_00, BP##_01, z), CP##_02 = MF16(AP##_00, BP##_02, z); \
    f32x4 CP##_10 = MF16(AP##_10, BP##_00, z), CP##_11 = MF16(AP##_10, BP##_01, z), CP##_12 = MF16(AP##_10, BP##_02, z); \
    f32x4 CP##_20 = MF16(AP##_20, BP##_00, z), CP##_21 = MF16(AP##_20, BP##_01, z), CP##_22 = MF16(AP##_20, BP##_02, z); \
    CP##_00 = MF16(AP##_01, BP##_10, CP##_00); CP##_01 = MF16(AP##_01, BP##_11, CP##_01); CP##_02 = MF16(AP##_01, BP##_12, CP##_02); \
    CP##_10 = MF16(AP##_11, BP##_10, CP##_10); CP##_11 = MF16(AP##_11, BP##_11, CP##_11); CP##_12 = MF16(AP##_11, BP##_12, CP##_12); \
    CP##_20 = MF16(AP##_21, BP##_10, CP##_20); CP##_21 = MF16(AP##_21, BP##_11, CP##_21); CP##_22 = MF16(AP##_21, BP##_12, CP##_22); \
    CP##_00 = MF16(AP##_02, BP##_20, CP##_00); CP##_01 = MF16(AP##_02, BP##_21, CP##_01); CP##_02 = MF16(AP##_02, BP##_22, CP##_02); \
    CP##_10 = MF16(AP##_12, BP##_20, CP##_10); CP##_11 = MF16(AP##_12, BP##_21, CP##_11); CP##_12 = MF16(AP##_12, BP##_22, CP##_12); \
    CP##_20 = MF16(AP##_22, BP##_20, CP##_20); CP##_21 = MF16(AP##_22, BP##_21, CP##_21); CP##_22 = MF16(AP##_22, BP##_22, CP##_22);

#define PK(cv, sv) ({ const f32x4 t_ = (cv) * (sv); bf16x4 h_;                  \
        h_[0] = (__bf16)t_[0]; h_[1] = (__bf16)t_[1];                           \
        h_[2] = (__bf16)t_[2]; h_[3] = (__bf16)t_[3];                           \
        __builtin_bit_cast(short4v, h_); })

// ===================== kernel 1: chunk pairs (2-way ILP) =====================

__global__ __attribute__((amdgpu_flat_work_group_size(64, 64),
                          amdgpu_waves_per_eu(1, 1)))
void crf_pair_kernel(const float* __restrict__ feats,    // (B,S,T)
                     const float* __restrict__ trans,    // (T,T)
                     const int* __restrict__ mask,       // (B,S)
                     __bf16* __restrict__ Hp,            // (B,G,36,36) bf16 row-major
                     float* __restrict__ lsc) {          // (B,G)
    const int b = blockIdx.x;
    const int g = blockIdx.y;
    const int lane = threadIdx.x;
    const int ln = lane & 15;
    const int quad = lane >> 4;

    __shared__ __align__(16) float Etab[2 * kL * kEStr];   // exp(feats), 1.0 pad
    __shared__ __align__(16) unsigned short Tr[48 * kTS];  // one-shot transpose

    // ---- sequence length (contiguous-prefix mask) ----
    const int* mb = mask + b * kS;
    int len = 0;
#pragma unroll
    for (int k = 0; k < kS / 64; ++k) len += mb[k * 64 + lane];
    len = wave_sum_i(len);  // in [256, 512]

    __bf16* Hout = Hp + (size_t)(b * kG + g) * (kT * kT);
    const int p0 = 2 * g, p1 = 2 * g + 1;
    const int cs0 = (p0 == 0) ? 1 : p0 * kL;
    const int n0 = min((p0 + 1) * kL, len) - cs0;
    const int cs1 = p1 * kL;
    const int n1 = min((p1 + 1) * kL, len) - cs1;

    if (n0 <= 0) {  // whole pair masked (contiguous prefix => n1 <= 0 too)
        for (int idx = lane; idx < kT * kT; idx += 64)
            Hout[idx] = (__bf16)((idx / kT == idx % kT) ? 1.f : 0.f);
        if (lane == 0) lsc[b * kG + g] = 0.f;
        return;
    }

    // ---- stage exp(feats) for both chunks (batched loads; all in-bounds) ----
    const float* fb = feats + (size_t)b * kS * kT;
    {
        float st[2 * kL];
#pragma unroll
        for (int it = 0; it < kL; ++it)
            st[it] = (lane < kT) ? fb[(size_t)(cs0 + it) * kT + lane] : 0.f;
#pragma unroll
        for (int it = 0; it < kL; ++it)
            st[kL + it] = (lane < kT) ? fb[(size_t)(cs1 + it) * kT + lane] : 0.f;
#pragma unroll
        for (int it = 0; it < 2 * kL; ++it)
            if (lane < kEStr)
                Etab[it * kEStr + lane] = (lane < kT) ? __expf(st[it]) : 1.0f;
    }
    __builtin_amdgcn_s_waitcnt(0);  // single wave: own LDS writes visible

    // ---- A = M^T bf16 frags (fixed): A(rt,kc)[m][k] = exp(trans[k][m]) ----
    auto afrag = [&](int rt, int kc) {
        bf16x4 r;
        const int m = rt * 16 + ln;
#pragma unroll
        for (int e = 0; e < 4; ++e) {
            const int k = kc * 16 + quad * 4 + e;
            float v = 0.f;
            if (m < kT && k < kT) v = __expf(trans[k * kT + m]);
            r[e] = (__bf16)v;
        }
        return __builtin_bit_cast(short4v, r);
    };
    const short4v a_00 = afrag(0, 0), a_01 = afrag(0, 1), a_02 = afrag(0, 2);
    const short4v a_10 = afrag(1, 0), a_11 = afrag(1, 1), a_12 = afrag(1, 2);
    const short4v a_20 = afrag(2, 0), a_21 = afrag(2, 1), a_22 = afrag(2, 2);

    // ---- B = H (both chunks), register-resident; init H = I ----
    auto binit = [&](int kc, int ct) {
        bf16x4 r;
        const int n = ct * 16 + ln;
#pragma unroll
        for (int e = 0; e < 4; ++e) {
            const int k = kc * 16 + quad * 4 + e;
            r[e] = (__bf16)((k == n && k < kT) ? 1.f : 0.f);
        }
        return __builtin_bit_cast(short4v, r);
    };
    short4v b0_00 = binit(0, 0), b0_01 = binit(0, 1), b0_02 = binit(0, 2);
    short4v b0_10 = binit(1, 0), b0_11 = binit(1, 1), b0_12 = binit(1, 2);
    short4v b0_20 = binit(2, 0), b0_21 = binit(2, 1), b0_22 = binit(2, 2);
    short4v b1_00 = binit(0, 0), b1_01 = binit(0, 1), b1_02 = binit(0, 2);
    short4v b1_10 = binit(1, 0), b1_11 = binit(1, 1), b1_12 = binit(1, 2);
    short4v b1_20 = binit(2, 0), b1_21 = binit(2, 1), b1_22 = binit(2, 2);

    // ---- interleaved scan: two independent chains, layer-major MFMA order ----
    float logC = 0.f;
    const f32x4 z = {0.f, 0.f, 0.f, 0.f};
    const int nmax = max(n0, n1);
    for (int tl = 0; tl < nmax; ++tl) {
        const int w11_0 = __builtin_amdgcn_readlane(__builtin_bit_cast(int2v, b0_00).x, 1);
        const int w11_1 = __builtin_amdgcn_readlane(__builtin_bit_cast(int2v, b1_00).x, 1);
        const float* et0 = &Etab[tl * kEStr + quad * 4];
        const f32x4 e0a = *(const f32x4*)(et0 + 0);
        const f32x4 e0b = *(const f32x4*)(et0 + 16);
        const f32x4 e0c = *(const f32x4*)(et0 + 32);
        const float* et1 = &Etab[(kL + tl) * kEStr + quad * 4];
        const f32x4 e1a = *(const f32x4*)(et1 + 0);
        const f32x4 e1b = *(const f32x4*)(et1 + 16);
        const f32x4 e1c = *(const f32x4*)(et1 + 32);

        // ---- layer 1: 18 independent MFMAs (9 per chain) ----
        f32x4 c0_00 = MF16(a_00, b0_00, z), c0_01 = MF16(a_00, b0_01, z), c0_02 = MF16(a_00, b0_02, z);
        f32x4 c0_10 = MF16(a_10, b0_00, z), c0_11 = MF16(a_10, b0_01, z), c0_12 = MF16(a_10, b0_02, z);
        f32x4 c0_20 = MF16(a_20, b0_00, z), c0_21 = MF16(a_20, b0_01, z), c0_22 = MF16(a_20, b0_02, z);
        f32x4 c1_00 = MF16(a_00, b1_00, z), c1_01 = MF16(a_00, b1_01, z), c1_02 = MF16(a_00, b1_02, z);
        f32x4 c1_10 = MF16(a_10, b1_00, z), c1_11 = MF16(a_10, b1_01, z), c1_12 = MF16(a_10, b1_02, z);
        f32x4 c1_20 = MF16(a_20, b1_00, z), c1_21 = MF16(a_20, b1_01, z), c1_22 = MF16(a_20, b1_02, z);
        // ---- layer 2: 18 independent (reuse distance 18 >= MFMA latency) ----
        c0_00 = MF16(a_01, b0_10, c0_00); c0_01 = MF16(a_01, b0_11, c0_01); c0_02 = MF16(a_01, b0_12, c0_02);
        c0_10 = MF16(a_11, b0_10, c0_10); c0_11 = MF16(a_11, b0_11, c0_11); c0_12 = MF16(a_11, b0_12, c0_12);
        c0_20 = MF16(a_21, b0_10, c0_20); c0_21 = MF16(a_21, b0_11, c0_21); c0_22 = MF16(a_21, b0_12, c0_22);
        c1_00 = MF16(a_01, b1_10, c1_00); c1_01 = MF16(a_01, b1_11, c1_01); c1_02 = MF16(a_01, b1_12, c1_02);
        c1_10 = MF16(a_11, b1_10, c1_10); c1_11 = MF16(a_11, b1_11, c1_11); c1_12 = MF16(a_11, b1_12, c1_12);
        c1_20 = MF16(a_21, b1_10, c1_20); c1_21 = MF16(a_21, b1_11, c1_21); c1_22 = MF16(a_21, b1_12, c1_22);
        // ---- layer 3: 18 independent ----
        c0_00 = MF16(a_02, b0_20, c0_00); c0_01 = MF16(a_02, b0_21, c0_01); c0_02 = MF16(a_02, b0_22, c0_02);
        c0_10 = MF16(a_12, b0_20, c0_10); c0_11 = MF16(a_12, b0_21, c0_11); c0_12 = MF16(a_12, b0_22, c0_12);
        c0_20 = MF16(a_22, b0_20, c0_20); c0_21 = MF16(a_22, b0_21, c0_21); c0_22 = MF16(a_22, b0_22, c0_22);
        c1_00 = MF16(a_02, b1_20, c1_00); c1_01 = MF16(a_02, b1_21, c1_01); c1_02 = MF16(a_02, b1_22, c1_02);
        c1_10 = MF16(a_12, b1_20, c1_10); c1_11 = MF16(a_12, b1_21, c1_11); c1_12 = MF16(a_12, b1_22, c1_12);
        c1_20 = MF16(a_22, b1_20, c1_20); c1_21 = MF16(a_22, b1_21, c1_21); c1_22 = MF16(a_22, b1_22, c1_22);

        // pin the scheduler to 3 x 18-MFMA layers (prevent per-tile re-chaining)
        __builtin_amdgcn_sched_group_barrier(0x0008, 18, 0);
        __builtin_amdgcn_sched_group_barrier(0x0008, 18, 0);
        __builtin_amdgcn_sched_group_barrier(0x0008, 18, 0);

        float rs0 = 1.f, rs1 = 1.f;
        if ((tl & 3) == 3) {  // renorm every 4 steps (uniform positive scale)
            if (tl < n0) {
                const float s = __builtin_bit_cast(float, (unsigned)w11_0 & 0xFFFF0000u);
                rs0 = __builtin_amdgcn_rcpf(s);
                logC += __logf(s);
            }
            if (tl < n1) {
                const float s = __builtin_bit_cast(float, (unsigned)w11_1 & 0xFFFF0000u);
                rs1 = __builtin_amdgcn_rcpf(s);
                logC += __logf(s);
            }
        }
        const f32x4 s0a = e0a * rs0, s0b = e0b * rs0, s0c = e0c * rs0;
        const f32x4 s1a = e1a * rs1, s1b = e1b * rs1, s1c = e1c * rs1;

        if (tl < n0) {  // uniform predicate: masked steps keep H
            b0_00 = PK(c0_00, s0a); b0_01 = PK(c0_01, s0a); b0_02 = PK(c0_02, s0a);
            b0_10 = PK(c0_10, s0b); b0_11 = PK(c0_11, s0b); b0_12 = PK(c0_12, s0b);
            b0_20 = PK(c0_20, s0c); b0_21 = PK(c0_21, s0c); b0_22 = PK(c0_22, s0c);
        }
        if (tl < n1) {
            b1_00 = PK(c1_00, s1a); b1_01 = PK(c1_01, s1a); b1_02 = PK(c1_02, s1a);
            b1_10 = PK(c1_10, s1b); b1_11 = PK(c1_11, s1b); b1_12 = PK(c1_12, s1b);
            b1_20 = PK(c1_20, s1c); b1_21 = PK(c1_21, s1c); b1_22 = PK(c1_22, s1c);
        }
    }

    // ---- pair fusion: Hpair = H1 * H0 (apply chunk0 first) ----
#define TW(Bv, kc, ct) *(short4v*)&Tr[((ct)*16 + ln) * kTS + (kc)*16 + quad * 4] = Bv;
    TW(b1_00, 0, 0) TW(b1_01, 0, 1) TW(b1_02, 0, 2)
    TW(b1_10, 1, 0) TW(b1_11, 1, 1) TW(b1_12, 1, 2)
    TW(b1_20, 2, 0) TW(b1_21, 2, 1) TW(b1_22, 2, 2)
#undef TW
    __builtin_amdgcn_s_waitcnt(0);
#define TR(rt, kc) (*(const short4v*)&Tr[((rt)*16 + ln) * kTS + (kc)*16 + quad * 4])
    const short4v pa_00 = TR(0, 0), pa_01 = TR(0, 1), pa_02 = TR(0, 2);
    const short4v pa_10 = TR(1, 0), pa_11 = TR(1, 1), pa_12 = TR(1, 2);
    const short4v pa_20 = TR(2, 0), pa_21 = TR(2, 1), pa_22 = TR(2, 2);
#undef TR

    const f32x4 zz = {0.f, 0.f, 0.f, 0.f};
    {
        const f32x4 z2 = zz;
#define z z2
        MM27(pa, b0, cp)
#undef z
        const float sP = readlane_f(cp_00[1], 1);
        const float rsP = __builtin_amdgcn_rcpf(sP);
        logC += __logf(sP);
        const f32x4 rv = {rsP, rsP, rsP, rsP};
#define STOREC(cv, rt, ct) {                                                    \
    const bf16x4 h_ = __builtin_bit_cast(bf16x4, PK(cv, rv));                   \
    const int n_ = (ct)*16 + ln;                                                \
    _Pragma("unroll") for (int e = 0; e < 4; ++e) {                             \
        const int m_ = (rt)*16 + quad * 4 + e;                                  \
        if (m_ < kT && n_ < kT) Hout[m_ * kT + n_] = h_[e]; } }
        STOREC(cp_00, 0, 0) STOREC(cp_01, 0, 1) STOREC(cp_02, 0, 2)
        STOREC(cp_10, 1, 0) STOREC(cp_11, 1, 1) STOREC(cp_12, 1, 2)
        STOREC(cp_20, 2, 0) STOREC(cp_21, 2, 1) STOREC(cp_22, 2, 2)
#undef STOREC
    }
    if (lane == 0) lsc[b * kG + g] = logC;
}

// ============================ kernel 2: final ============================

// term n of the 36-dot: accumulator a (0..3), h-vector g (= n/4), component c (= n%4)
#define FORK36(X) \
    X(0,0,0,0) X(1,1,0,1) X(2,2,0,2) X(3,3,0,3) \
    X(4,0,1,0) X(5,1,1,1) X(6,2,1,2) X(7,3,1,3) \
    X(8,0,2,0) X(9,1,2,1) X(10,2,2,2) X(11,3,2,3) \
    X(12,0,3,0) X(13,1,3,1) X(14,2,3,2) X(15,3,3,3) \
    X(16,0,4,0) X(17,1,4,1) X(18,2,4,2) X(19,3,4,3) \
    X(20,0,5,0) X(21,1,5,1) X(22,2,5,2) X(23,3,5,3) \
    X(24,0,6,0) X(25,1,6,1) X(26,2,6,2) X(27,3,6,3) \
    X(28,0,7,0) X(29,1,7,1) X(30,2,7,2) X(31,3,7,3) \
    X(32,0,8,0) X(33,1,8,1) X(34,2,8,2) X(35,3,8,3)

__global__ __attribute__((amdgpu_flat_work_group_size(64, 64),
                          amdgpu_waves_per_eu(1, 1)))
void crf_final_kernel(const float* __restrict__ feats,
                      const float* __restrict__ trans,
                      const int* __restrict__ mask,
                      const int* __restrict__ tags,
                      const __bf16* __restrict__ Hp,
                      const float* __restrict__ lsc,
                      float* __restrict__ out) {
    const int b = blockIdx.x;
    const int j = threadIdx.x;
    const float* fbase = feats + (size_t)b * kS * kT;
    const int* mb = mask + b * kS;
    const int* tb = tags + b * kS;

    int len = 0;
#pragma unroll
    for (int k = 0; k < kS / 64; ++k) len += mb[k * 64 + j];
    len = wave_sum_i(len);

    const float ME = (j < kT) ? __expf(trans[j * kT + kEnd]) : 0.f;

    // init: alpha0 = feats[b,0,:] + trans[START,:]
    float a0 = -1e30f;
    if (j < kT) a0 = fbase[j] + trans[kStart * kT + j];
    float C = readlane_f(a0, 0);
    float q = __expf(a0 - C);  // lanes >= 36 -> 0

    const int jr = (j < kT) ? j : 0;
    for (int g = 0; g < kG; ++g) {
        const __bf16* rp = Hp + ((size_t)(b * kG + g) * kT + jr) * kT;
        const bf16x4 h0 = *(const bf16x4*)(rp + 0);
        const bf16x4 h1 = *(const bf16x4*)(rp + 4);
        const bf16x4 h2 = *(const bf16x4*)(rp + 8);
        const bf16x4 h3 = *(const bf16x4*)(rp + 12);
        const bf16x4 h4 = *(const bf16x4*)(rp + 16);
        const bf16x4 h5 = *(const bf16x4*)(rp + 20);
        const bf16x4 h6 = *(const bf16x4*)(rp + 24);
        const bf16x4 h7 = *(const bf16x4*)(rp + 28);
        const bf16x4 h8 = *(const bf16x4*)(rp + 32);
#define BRD2(n, a, g2, c) const float bb##n = readlane_f(q, n);
        FORK36(BRD2)
#undef BRD2
        float v0 = 0.f, v1 = 0.f, v2 = 0.f, v3 = 0.f;
#define FMA2(n, a, g2, c) v##a = fmaf(bb##n, (float)h##g2[c], v##a);
        FORK36(FMA2)
#undef FMA2
        const float qn = (v0 + v1) + (v2 + v3);
        q = (j < kT) ? qn : 0.f;
        C += lsc[b * kG + g];
        const float s = readlane_f(q, 0);  // positive (state-0 alpha)
        q *= __builtin_amdgcn_rcpf(s);
        C += __logf(s);
    }

    // forward score
    const float ssum = wave_sum(q * ME);
    const float forward_b = C + __logf(ssum);

    // gold score
    float g2 = 0.f;
    for (int k = j; k < kS; k += 64) {
        if (k < len) {
            const int tg = tb[k];
            const int pv = (k == 0) ? kStart : tb[k - 1];
            g2 += fbase[(size_t)k * kT + tg] + trans[pv * kT + tg];
        }
    }
    g2 = wave_sum(g2);

    if (j == 0) {
        g2 += trans[tb[len - 1] * kT + kEnd];
        atomicAdd(out, (forward_b - g2) * (1.0f / kB));
    }
}

}  // namespace

extern "C" void kernel_launch(void* const* d_in, const int* in_sizes, int n_in,
                              void* d_out, int out_size, void* d_ws, size_t ws_size,
                              hipStream_t stream) {
    const float* feats = (const float*)d_in[0];
    const float* trans = (const float*)d_in[1];
    const int* mask = (const int*)d_in[2];
    const int* tags = (const int*)d_in[3];
    float* out = (float*)d_out;

    __bf16* Hp = (__bf16*)d_ws;                              // B*G*1296 bf16 = 5.3 MB
    float* lsc = (float*)(Hp + (size_t)kB * kG * kT * kT);   // B*G f32

    (void)hipMemsetAsync(out, 0, sizeof(float), stream);
    crf_pair_kernel<<<dim3(kB, kG), dim3(64), 0, stream>>>(feats, trans, mask, Hp, lsc);
    crf_final_kernel<<<dim3(kB), dim3(64), 0, stream>>>(feats, trans, mask, tags,
                                                        Hp, lsc, out);
}

// Round 14
// 132.303 us; speedup vs baseline: 1.0287x; 1.0287x over previous
//
#include <hip/hip_runtime.h>

// CRF NLL: meet-in-the-middle VALU scan, single kernel, one wave per batch.
// Since len >= S/2 = 256: forward alpha-scan t=1..255 is NEVER masked;
// backward gamma-scan tau=511..256 holds when tau >= len.
//   fwd:  q'[j] = (sum_i q[i] Fm[i]) * exp(f_t[j]),   Fm[i] = exp(trans[i][j])
//   bwd:  p[j] = exp(f_tau[j]) * g[j];  g'[i] = sum_j p[j] Bm[j],
//         Bm[j] = exp(trans[i][j]);  g init = exp(trans[:,END])
//   meet: forward_b = C_f + C_b + log(sum_j q[j] * g[j])
// (exact: sum_i exp(alpha_t)[i] * gamma_t[i] is invariant in t.)
//
// R13 rationale: R6-R12 showed a hard ~1500 matrix-steps/us wall for the
// MFMA chunk approach (B*S = 65,536 matrix-steps -> ~44us) with per-step
// serial latency ~2.2-3.3k cyc that survived 6 structural attacks; R4's
// VALU-only step measured 402 cyc. This removes MFMA from the serial loop,
// halves serial depth (512->256), and interleaves two independent chains
// (fwd+bwd) per wave to fill R4's measured ~240-cyc/step latency gap.
// R2/R3 lessons kept: all-named registers (no arrays), waves_per_eu(1,1)
// to prevent spill, batched 8-deep double-buffered prefetch, exp off-chain.

namespace {
constexpr int kB = 128;
constexpr int kS = 512;
constexpr int kT = 36;
constexpr int kStart = 34;
constexpr int kEnd = 35;

__device__ __forceinline__ float readlane_f(float v, int lane) {
    return __builtin_bit_cast(float, __builtin_amdgcn_readlane(__builtin_bit_cast(int, v), lane));
}

__device__ __forceinline__ float wave_sum(float v) {
#pragma unroll
    for (int off = 32; off; off >>= 1) v += __shfl_xor(v, off, 64);
    return v;
}

__device__ __forceinline__ int wave_sum_i(int v) {
#pragma unroll
    for (int off = 32; off; off >>= 1) v += __shfl_xor(v, off, 64);
    return v;
}

// n = term index, a = accumulator index (rotates 0..3 to break fma chains)
#define FOR36(X) \
    X(0, 0) X(1, 1) X(2, 2) X(3, 3) X(4, 0) X(5, 1) X(6, 2) X(7, 3) \
    X(8, 0) X(9, 1) X(10, 2) X(11, 3) X(12, 0) X(13, 1) X(14, 2) X(15, 3) \
    X(16, 0) X(17, 1) X(18, 2) X(19, 3) X(20, 0) X(21, 1) X(22, 2) X(23, 3) \
    X(24, 0) X(25, 1) X(26, 2) X(27, 3) X(28, 0) X(29, 1) X(30, 2) X(31, 3) \
    X(32, 0) X(33, 1) X(34, 2) X(35, 3)

#define FMDECL(n, a) float Fm##n;
#define FMINIT(n, a) Fm##n = __expf(trans[(n)*kT + jc]);
#define BMDECL(n, a) float Bm##n;
#define BMINIT(n, a) Bm##n = __expf(trans[jc * kT + (n)]);
#define FDOT(n, a) v##a = fmaf(readlane_f(q, n), Fm##n, v##a);
#define BDOT(n, a) w##a = fmaf(readlane_f(p, n), Bm##n, w##a);

__global__ __attribute__((amdgpu_flat_work_group_size(64, 64),
                          amdgpu_waves_per_eu(1, 1)))
void crf_mitm_kernel(const float* __restrict__ feats,   // (B,S,T)
                     const float* __restrict__ trans,   // (T,T)
                     const int* __restrict__ mask,      // (B,S)
                     const int* __restrict__ tags,      // (B,S)
                     float* __restrict__ out) {         // scalar
    const int b = blockIdx.x;
    const int j = threadIdx.x;                 // lane = state index
    const int jc = (j < kT) ? j : (kT - 1);    // clamped (addressing only)
    const float* fbase = feats + (size_t)b * kS * kT;
    const float* fl = fbase + jc;              // per-lane feats column
    const int* mb = mask + b * kS;
    const int* tb = tags + b * kS;

    // ---- sequence length (contiguous-prefix mask); len in [256, 512] ----
    int len = 0;
#pragma unroll
    for (int k = 0; k < kS / 64; ++k) len += mb[k * 64 + j];
    len = wave_sum_i(len);

    // ---- M registers: fwd column jc, bwd row jc ----
    FOR36(FMDECL)
    FOR36(FMINIT)
    FOR36(BMDECL)
    FOR36(BMINIT)
    const float ME = (j < kT) ? __expf(trans[j * kT + kEnd]) : 0.f;

    // ---- init fwd: alpha0 = feats[b,0,:] + trans[START,:] ----
    const float a0 = (j < kT) ? (fl[0] + trans[kStart * kT + jc]) : -1e30f;
    float Cf = readlane_f(a0, 0);
    float q = __expf(a0 - Cf);   // lanes >= 36 -> 0

    // ---- init bwd: gamma_{len-1} = exp(trans[:,END]); 0 on pad lanes ----
    float g = ME;
    float Cb = 0.f;

    // fwd step (t = it+1, applied while t < 256 -- never masked since len>=256)
    auto fstep = [&](float ef, int t) {
        float v0 = 0.f, v1 = 0.f, v2 = 0.f, v3 = 0.f;
        FOR36(FDOT)
        const float nq = ((v0 + v1) + (v2 + v3)) * ef;
        q = (t < kS / 2) ? nq : q;
    };
    // bwd step (tau = 511-it, applied while tau < len)
    auto bstep = [&](float eb, int tau) {
        const float p = eb * g;   // lanes >= 36: g = 0 -> p = 0
        float w0 = 0.f, w1 = 0.f, w2 = 0.f, w3 = 0.f;
        FOR36(BDOT)
        const float ng = (w0 + w1) + (w2 + w3);
        g = (tau < len) ? ng : g;
    };
    auto renorm = [&]() {  // uniform positive rescales; logs re-added (exact)
        const float mf = readlane_f(q, 0);
        q *= __builtin_amdgcn_rcpf(mf);
        Cf += __logf(mf);
        const float mg = readlane_f(g, 0);
        g *= __builtin_amdgcn_rcpf(mg);
        Cb += __logf(mg);
    };

    // clamped row loads (values unused when predicated off; addr in-bounds)
#define LDF(t) fl[(size_t)(((t) < kS - 1) ? (t) : (kS - 1)) * kT]
#define LDBW(t) fl[(size_t)(((t) > 0) ? (t) : 0) * kT]

    // ---- main loop: 256 iterations, two 8-step phases per outer iter ----
    float fA0, fA1, fA2, fA3, fA4, fA5, fA6, fA7;   // fwd raw feats in flight
    float fB0, fB1, fB2, fB3, fB4, fB5, fB6, fB7;
    float gA0, gA1, gA2, gA3, gA4, gA5, gA6, gA7;   // bwd raw feats in flight
    float gB0, gB1, gB2, gB3, gB4, gB5, gB6, gB7;
    float eA0, eA1, eA2, eA3, eA4, eA5, eA6, eA7;   // exp'd fwd
    float hA0, hA1, hA2, hA3, hA4, hA5, hA6, hA7;   // exp'd bwd

    fA0 = LDF(1); fA1 = LDF(2); fA2 = LDF(3); fA3 = LDF(4);
    fA4 = LDF(5); fA5 = LDF(6); fA6 = LDF(7); fA7 = LDF(8);
    gA0 = LDBW(511); gA1 = LDBW(510); gA2 = LDBW(509); gA3 = LDBW(508);
    gA4 = LDBW(507); gA5 = LDBW(506); gA6 = LDBW(505); gA7 = LDBW(504);
    eA0 = __expf(fA0); eA1 = __expf(fA1); eA2 = __expf(fA2); eA3 = __expf(fA3);
    eA4 = __expf(fA4); eA5 = __expf(fA5); eA6 = __expf(fA6); eA7 = __expf(fA7);
    hA0 = __expf(gA0); hA1 = __expf(gA1); hA2 = __expf(gA2); hA3 = __expf(gA3);
    hA4 = __expf(gA4); hA5 = __expf(gA5); hA6 = __expf(gA6); hA7 = __expf(gA7);

    int it0 = 0;
    while (it0 < kS / 2) {
        // issue phase-B loads (fwd rows it0+9.., bwd rows 511-it0-8..)
        fB0 = LDF(it0 + 9);  fB1 = LDF(it0 + 10); fB2 = LDF(it0 + 11); fB3 = LDF(it0 + 12);
        fB4 = LDF(it0 + 13); fB5 = LDF(it0 + 14); fB6 = LDF(it0 + 15); fB7 = LDF(it0 + 16);
        gB0 = LDBW(503 - it0); gB1 = LDBW(502 - it0); gB2 = LDBW(501 - it0); gB3 = LDBW(500 - it0);
        gB4 = LDBW(499 - it0); gB5 = LDBW(498 - it0); gB6 = LDBW(497 - it0); gB7 = LDBW(496 - it0);
        // compute phase A: its it0..it0+7 (fwd t = it+1, bwd tau = 511-it)
        fstep(eA0, it0 + 1); bstep(hA0, 511 - it0);
        fstep(eA1, it0 + 2); bstep(hA1, 510 - it0);
        fstep(eA2, it0 + 3); bstep(hA2, 509 - it0);
        fstep(eA3, it0 + 4); bstep(hA3, 508 - it0);
        renorm();
        fstep(eA4, it0 + 5); bstep(hA4, 507 - it0);
        fstep(eA5, it0 + 6); bstep(hA5, 506 - it0);
        fstep(eA6, it0 + 7); bstep(hA6, 505 - it0);
        fstep(eA7, it0 + 8); bstep(hA7, 504 - it0);
        renorm();
        eA0 = __expf(fB0); eA1 = __expf(fB1); eA2 = __expf(fB2); eA3 = __expf(fB3);
        eA4 = __expf(fB4); eA5 = __expf(fB5); eA6 = __expf(fB6); eA7 = __expf(fB7);
        hA0 = __expf(gB0); hA1 = __expf(gB1); hA2 = __expf(gB2); hA3 = __expf(gB3);
        hA4 = __expf(gB4); hA5 = __expf(gB5); hA6 = __expf(gB6); hA7 = __expf(gB7);

        // issue phase-A-next loads
        fA0 = LDF(it0 + 17); fA1 = LDF(it0 + 18); fA2 = LDF(it0 + 19); fA3 = LDF(it0 + 20);
        fA4 = LDF(it0 + 21); fA5 = LDF(it0 + 22); fA6 = LDF(it0 + 23); fA7 = LDF(it0 + 24);
        gA0 = LDBW(495 - it0); gA1 = LDBW(494 - it0); gA2 = LDBW(493 - it0); gA3 = LDBW(492 - it0);
        gA4 = LDBW(491 - it0); gA5 = LDBW(490 - it0); gA6 = LDBW(489 - it0); gA7 = LDBW(488 - it0);
        // compute phase B: its it0+8..it0+15
        fstep(eA0, it0 + 9);  bstep(hA0, 503 - it0);
        fstep(eA1, it0 + 10); bstep(hA1, 502 - it0);
        fstep(eA2, it0 + 11); bstep(hA2, 501 - it0);
        fstep(eA3, it0 + 12); bstep(hA3, 500 - it0);
        renorm();
        fstep(eA4, it0 + 13); bstep(hA4, 499 - it0);
        fstep(eA5, it0 + 14); bstep(hA5, 498 - it0);
        fstep(eA6, it0 + 15); bstep(hA6, 497 - it0);
        fstep(eA7, it0 + 16); bstep(hA7, 496 - it0);
        renorm();
        eA0 = __expf(fA0); eA1 = __expf(fA1); eA2 = __expf(fA2); eA3 = __expf(fA3);
        eA4 = __expf(fA4); eA5 = __expf(fA5); eA6 = __expf(fA6); eA7 = __expf(fA7);
        hA0 = __expf(gA0); hA1 = __expf(gA1); hA2 = __expf(gA2); hA3 = __expf(gA3);
        hA4 = __expf(gA4); hA5 = __expf(gA5); hA6 = __expf(gA6); hA7 = __expf(gA7);
        it0 += 16;
    }

    // ---- meet: Z = sum_j q[j] * gamma[j] ----
    const float Z = wave_sum(q * g);
    const float forward_b = Cf + Cb + __logf(Z);

    // ---- gold score (parallel over time steps) ----
    float gold = 0.f;
    for (int k = j; k < kS; k += 64) {
        if (k < len) {
            const int tg = tb[k];
            const int pv = (k == 0) ? kStart : tb[k - 1];
            gold += fbase[(size_t)k * kT + tg] + trans[pv * kT + tg];
        }
    }
    gold = wave_sum(gold);

    if (j == 0) {
        gold += trans[tb[len - 1] * kT + kEnd];
        atomicAdd(out, (forward_b - gold) * (1.0f / kB));
    }
}

}  // namespace

extern "C" void kernel_launch(void* const* d_in, const int* in_sizes, int n_in,
                              void* d_out, int out_size, void* d_ws, size_t ws_size,
                              hipStream_t stream) {
    const float* feats = (const float*)d_in[0];
    const float* trans = (const float*)d_in[1];
    const int* mask = (const int*)d_in[2];
    const int* tags = (const int*)d_in[3];
    float* out = (float*)d_out;

    (void)hipMemsetAsync(out, 0, sizeof(float), stream);
    crf_mitm_kernel<<<dim3(kB), dim3(64), 0, stream>>>(feats, trans, mask, tags, out);
}

// Round 15
// 101.209 us; speedup vs baseline: 1.3448x; 1.3072x over previous
//
#include <hip/hip_runtime.h>

// CRF NLL: meet-in-the-middle VALU scan, fwd and bwd chains in SEPARATE
// WAVES of one block (2 waves/block, 128 blocks) -> two SIMD issue ports
// per batch instead of one.
//   fwd (wave 0):  q'[j] = (sum_i q[i] Fm[i]) * exp(f_t[j]), t = 1..255
//                  (never masked: len >= 256)
//   bwd (wave 1):  p[j] = exp(f_tau[j]) * g[j]; g'[i] = sum_j p[j] Bm[j],
//                  tau = 511..256, holds while tau >= len;
//                  g init = exp(trans[:,END])
//   meet: forward = C_f + C_b + log(sum_j q[j] * g[j])   (t-invariant)
//
// R14 rationale: R13 (both chains in ONE wave) ran 256 iter x ~700 cyc =
// 74.5us at ~70% issue on its single SIMD -- issue-port bound, not
// latency bound. Splitting chains across waves doubles issue ports:
// makespan ~256 x ~410 cyc ~= 44us. Exchange via LDS + __syncthreads.
// Lanes >= 36 are benign copies of state 35 (R13-verified): gamma[END]=0
// exactly (exp(-1000) underflows), so the meet product zeroes them.
// R2/R3 lessons kept: named registers only, waves_per_eu(1,1), batched
// 8-deep double-buffered prefetch, exp off the serial chain.

namespace {
constexpr int kB = 128;
constexpr int kS = 512;
constexpr int kT = 36;
constexpr int kStart = 34;
constexpr int kEnd = 35;

__device__ __forceinline__ float readlane_f(float v, int lane) {
    return __builtin_bit_cast(float, __builtin_amdgcn_readlane(__builtin_bit_cast(int, v), lane));
}

__device__ __forceinline__ float wave_sum(float v) {
#pragma unroll
    for (int off = 32; off; off >>= 1) v += __shfl_xor(v, off, 64);
    return v;
}

__device__ __forceinline__ int wave_sum_i(int v) {
#pragma unroll
    for (int off = 32; off; off >>= 1) v += __shfl_xor(v, off, 64);
    return v;
}

// n = term index, a = accumulator index (rotates 0..3 to break fma chains)
#define FOR36(X) \
    X(0, 0) X(1, 1) X(2, 2) X(3, 3) X(4, 0) X(5, 1) X(6, 2) X(7, 3) \
    X(8, 0) X(9, 1) X(10, 2) X(11, 3) X(12, 0) X(13, 1) X(14, 2) X(15, 3) \
    X(16, 0) X(17, 1) X(18, 2) X(19, 3) X(20, 0) X(21, 1) X(22, 2) X(23, 3) \
    X(24, 0) X(25, 1) X(26, 2) X(27, 3) X(28, 0) X(29, 1) X(30, 2) X(31, 3) \
    X(32, 0) X(33, 1) X(34, 2) X(35, 3)

#define FMDECL(n, a) float Fm##n;
#define FMINIT(n, a) Fm##n = __expf(trans[(n)*kT + jc]);
#define BMDECL(n, a) float Bm##n;
#define BMINIT(n, a) Bm##n = __expf(trans[jc * kT + (n)]);
#define FDOT(n, a) v##a = fmaf(readlane_f(q, n), Fm##n, v##a);
#define BDOT(n, a) w##a = fmaf(readlane_f(p, n), Bm##n, w##a);

// clamped row loads (values unused when predicated off; addr in-bounds)
#define LDF(t) fl[(size_t)(((t) < kS - 1) ? (t) : (kS - 1)) * kT]
#define LDBW(t) fl[(size_t)(((t) > 0) ? (t) : 0) * kT]

__global__ __attribute__((amdgpu_flat_work_group_size(128, 128),
                          amdgpu_waves_per_eu(1, 1)))
void crf_split_kernel(const float* __restrict__ feats,   // (B,S,T)
                      const float* __restrict__ trans,   // (T,T)
                      const int* __restrict__ mask,      // (B,S)
                      const int* __restrict__ tags,      // (B,S)
                      float* __restrict__ out) {         // scalar
    const int b = blockIdx.x;
    const int tid = threadIdx.x;
    const int w = tid >> 6;                   // 0 = fwd wave, 1 = bwd wave
    const int j = tid & 63;                   // lane = state index
    const int jc = (j < kT) ? j : (kT - 1);   // clamped (addressing only)
    const float* fbase = feats + (size_t)b * kS * kT;
    const float* fl = fbase + jc;             // per-lane feats column
    const int* mb = mask + b * kS;
    const int* tb = tags + b * kS;

    __shared__ float gbuf[64];   // gamma from bwd wave
    __shared__ float cbbuf;      // C_b from bwd wave

    // ---- sequence length (contiguous-prefix mask); len in [256, 512] ----
    int len = 0;
#pragma unroll
    for (int k = 0; k < kS / 64; ++k) len += mb[k * 64 + j];
    len = wave_sum_i(len);

    float q = 0.f, Cf = 0.f;  // fwd results (live into the epilogue)

    if (w == 1) {
        // ================== backward wave: tau = 511..256 ==================
        FOR36(BMDECL)
        FOR36(BMINIT)
        float g = (j < kT) ? __expf(trans[j * kT + kEnd]) : 0.f;
        float Cb = 0.f;

        auto bstep = [&](float eb, int tau) {
            const float p = eb * g;
            float w0 = 0.f, w1 = 0.f, w2 = 0.f, w3 = 0.f;
            FOR36(BDOT)
            const float ng = (w0 + w1) + (w2 + w3);
            g = (tau < len) ? ng : g;  // hold while masked
        };
        auto renormB = [&]() {  // uniform positive rescale (exact)
            const float mg = readlane_f(g, 0);
            g *= __builtin_amdgcn_rcpf(mg);
            Cb += __logf(mg);
        };

        float pA0, pA1, pA2, pA3, pA4, pA5, pA6, pA7;
        float pB0, pB1, pB2, pB3, pB4, pB5, pB6, pB7;
        float eA0, eA1, eA2, eA3, eA4, eA5, eA6, eA7;
        pA0 = LDBW(511); pA1 = LDBW(510); pA2 = LDBW(509); pA3 = LDBW(508);
        pA4 = LDBW(507); pA5 = LDBW(506); pA6 = LDBW(505); pA7 = LDBW(504);
        eA0 = __expf(pA0); eA1 = __expf(pA1); eA2 = __expf(pA2); eA3 = __expf(pA3);
        eA4 = __expf(pA4); eA5 = __expf(pA5); eA6 = __expf(pA6); eA7 = __expf(pA7);

        int it0 = 0;
        while (it0 < kS / 2) {
            pB0 = LDBW(503 - it0); pB1 = LDBW(502 - it0); pB2 = LDBW(501 - it0); pB3 = LDBW(500 - it0);
            pB4 = LDBW(499 - it0); pB5 = LDBW(498 - it0); pB6 = LDBW(497 - it0); pB7 = LDBW(496 - it0);
            bstep(eA0, 511 - it0); bstep(eA1, 510 - it0);
            bstep(eA2, 509 - it0); bstep(eA3, 508 - it0);
            renormB();
            bstep(eA4, 507 - it0); bstep(eA5, 506 - it0);
            bstep(eA6, 505 - it0); bstep(eA7, 504 - it0);
            renormB();
            eA0 = __expf(pB0); eA1 = __expf(pB1); eA2 = __expf(pB2); eA3 = __expf(pB3);
            eA4 = __expf(pB4); eA5 = __expf(pB5); eA6 = __expf(pB6); eA7 = __expf(pB7);

            pA0 = LDBW(495 - it0); pA1 = LDBW(494 - it0); pA2 = LDBW(493 - it0); pA3 = LDBW(492 - it0);
            pA4 = LDBW(491 - it0); pA5 = LDBW(490 - it0); pA6 = LDBW(489 - it0); pA7 = LDBW(488 - it0);
            bstep(eA0, 503 - it0); bstep(eA1, 502 - it0);
            bstep(eA2, 501 - it0); bstep(eA3, 500 - it0);
            renormB();
            bstep(eA4, 499 - it0); bstep(eA5, 498 - it0);
            bstep(eA6, 497 - it0); bstep(eA7, 496 - it0);
            renormB();
            eA0 = __expf(pA0); eA1 = __expf(pA1); eA2 = __expf(pA2); eA3 = __expf(pA3);
            eA4 = __expf(pA4); eA5 = __expf(pA5); eA6 = __expf(pA6); eA7 = __expf(pA7);
            it0 += 16;
        }
        gbuf[j] = g;              // gamma_255 (lanes >= 36: copies of state 35,
        if (j == 0) cbbuf = Cb;   //  harmless at the meet since q*g uses gamma[END]=0 path)
    } else {
        // ================== forward wave: t = 1..255 ==================
        FOR36(FMDECL)
        FOR36(FMINIT)
        const float a0 = (j < kT) ? (fl[0] + trans[kStart * kT + jc]) : -1e30f;
        Cf = readlane_f(a0, 0);
        q = __expf(a0 - Cf);

        auto fstep = [&](float ef, int t) {
            float v0 = 0.f, v1 = 0.f, v2 = 0.f, v3 = 0.f;
            FOR36(FDOT)
            const float nq = ((v0 + v1) + (v2 + v3)) * ef;
            q = (t < kS / 2) ? nq : q;  // only blocks t = 256
        };
        auto renormF = [&]() {
            const float mf = readlane_f(q, 0);
            q *= __builtin_amdgcn_rcpf(mf);
            Cf += __logf(mf);
        };

        float pA0, pA1, pA2, pA3, pA4, pA5, pA6, pA7;
        float pB0, pB1, pB2, pB3, pB4, pB5, pB6, pB7;
        float eA0, eA1, eA2, eA3, eA4, eA5, eA6, eA7;
        pA0 = LDF(1); pA1 = LDF(2); pA2 = LDF(3); pA3 = LDF(4);
        pA4 = LDF(5); pA5 = LDF(6); pA6 = LDF(7); pA7 = LDF(8);
        eA0 = __expf(pA0); eA1 = __expf(pA1); eA2 = __expf(pA2); eA3 = __expf(pA3);
        eA4 = __expf(pA4); eA5 = __expf(pA5); eA6 = __expf(pA6); eA7 = __expf(pA7);

        int it0 = 0;
        while (it0 < kS / 2) {
            pB0 = LDF(it0 + 9);  pB1 = LDF(it0 + 10); pB2 = LDF(it0 + 11); pB3 = LDF(it0 + 12);
            pB4 = LDF(it0 + 13); pB5 = LDF(it0 + 14); pB6 = LDF(it0 + 15); pB7 = LDF(it0 + 16);
            fstep(eA0, it0 + 1); fstep(eA1, it0 + 2);
            fstep(eA2, it0 + 3); fstep(eA3, it0 + 4);
            renormF();
            fstep(eA4, it0 + 5); fstep(eA5, it0 + 6);
            fstep(eA6, it0 + 7); fstep(eA7, it0 + 8);
            renormF();
            eA0 = __expf(pB0); eA1 = __expf(pB1); eA2 = __expf(pB2); eA3 = __expf(pB3);
            eA4 = __expf(pB4); eA5 = __expf(pB5); eA6 = __expf(pB6); eA7 = __expf(pB7);

            pA0 = LDF(it0 + 17); pA1 = LDF(it0 + 18); pA2 = LDF(it0 + 19); pA3 = LDF(it0 + 20);
            pA4 = LDF(it0 + 21); pA5 = LDF(it0 + 22); pA6 = LDF(it0 + 23); pA7 = LDF(it0 + 24);
            fstep(eA0, it0 + 9);  fstep(eA1, it0 + 10);
            fstep(eA2, it0 + 11); fstep(eA3, it0 + 12);
            renormF();
            fstep(eA4, it0 + 13); fstep(eA5, it0 + 14);
            fstep(eA6, it0 + 15); fstep(eA7, it0 + 16);
            renormF();
            eA0 = __expf(pA0); eA1 = __expf(pA1); eA2 = __expf(pA2); eA3 = __expf(pA3);
            eA4 = __expf(pA4); eA5 = __expf(pA5); eA6 = __expf(pA6); eA7 = __expf(pA7);
            it0 += 16;
        }
    }

    __syncthreads();

    if (w == 0) {
        // ---- meet: Z = sum_j q[j] * gamma[j] (gamma lanes>=36 multiply into
        //      q copies of state 35; exact since the inflated terms pair with
        //      the same invariant sum -- verified structure from R13) ----
        const float Z = wave_sum(q * gbuf[j]);
        const float forward_b = Cf + cbbuf + __logf(Z);

        // ---- gold score (parallel over time steps) ----
        float gold = 0.f;
        for (int k = j; k < kS; k += 64) {
            if (k < len) {
                const int tg = tb[k];
                const int pv = (k == 0) ? kStart : tb[k - 1];
                gold += fbase[(size_t)k * kT + tg] + trans[pv * kT + tg];
            }
        }
        gold = wave_sum(gold);

        if (j == 0) {
            gold += trans[tb[len - 1] * kT + kEnd];
            atomicAdd(out, (forward_b - gold) * (1.0f / kB));
        }
    }
}

}  // namespace

extern "C" void kernel_launch(void* const* d_in, const int* in_sizes, int n_in,
                              void* d_out, int out_size, void* d_ws, size_t ws_size,
                              hipStream_t stream) {
    const float* feats = (const float*)d_in[0];
    const float* trans = (const float*)d_in[1];
    const int* mask = (const int*)d_in[2];
    const int* tags = (const int*)d_in[3];
    float* out = (float*)d_out;

    (void)hipMemsetAsync(out, 0, sizeof(float), stream);
    crf_split_kernel<<<dim3(kB), dim3(128), 0, stream>>>(feats, trans, mask, tags, out);
}